// Round 10
// baseline (1981.891 us; speedup 1.0000x reference)
//
#include <hip/hip_runtime.h>
#include <hip/hip_cooperative_groups.h>
#include <math.h>

namespace cg = cooperative_groups;

typedef __attribute__((ext_vector_type(8))) __bf16 bf16x8;
typedef __attribute__((ext_vector_type(4))) float f32x4;

__device__ inline unsigned short f2bf(float f) {  // RNE
    unsigned int i = __float_as_uint(f);
    unsigned int r = i + 0x7fffu + ((i >> 16) & 1u);
    return (unsigned short)(r >> 16);
}
__device__ inline float bf2f(unsigned short u) {
    return __uint_as_float(((unsigned int)u) << 16);
}
#define RL(v, l) __uint_as_float(__builtin_amdgcn_readlane(__float_as_uint(v), (l)))

struct Params {
    const float* x;
    const int* ei;
    const int* batch;
    const float *w1, *b1, *w2, *b2, *w3, *b3;
    const float* gw[5];
    const float* gas[5];
    const float* gad[5];
    const float* gb[5];
    const float *lw, *lb;
    float* out;
    int N, E, G;
    unsigned short* actA;
    unsigned short* actB;
    float* logit0;
    float* logit1;
    int* deg;
    int* rowptr;
    int* cursor;
    int* esrc;
    int* bsums;
    int* gstart;
    unsigned short* wbAll;
    float* uAll;
};

// ---------------- bf16 MFMA GEMM phase: 128xBN tiles, grid-stride over tiles ----------------
// If us != null (layer 0): by==0 tiles also emit as_[r] = A[r,:].us, ad_ likewise.
template <int BN>
__device__ void gemm_phase(const unsigned short* __restrict__ A,
                           const unsigned short* __restrict__ Wb,
                           unsigned short* __restrict__ Cb, const float* __restrict__ us,
                           const float* __restrict__ ud, float* __restrict__ as_,
                           float* __restrict__ ad_, int n, int K, int O, char* smem) {
    constexpr int SN = BN / 32;
    unsigned short(*As)[72] = (unsigned short(*)[72])smem;           // 128x72 bf16
    unsigned short(*Ws)[72] = (unsigned short(*)[72])(smem + 18432);  // BNx72 bf16
    int tid = threadIdx.x;
    int w = tid >> 6, lane = tid & 63;
    int wr = w >> 1, wc = w & 1;
    int quad = lane >> 4, l15 = lane & 15;
    int urow = tid & 127, uhalf = tid >> 7;
    int TX = (n + 127) / 128, TY = O / BN;
    int T = TX * TY;
    for (int t = blockIdx.x; t < T; t += gridDim.x) {
        int bx = t % TX, by = t / TX;
        int row0 = bx * 128, col0 = by * BN;
        bool doU = (us != nullptr) && (by == 0);
        f32x4 acc[4][SN];
#pragma unroll
        for (int mi = 0; mi < 4; mi++)
#pragma unroll
            for (int ni = 0; ni < SN; ni++) acc[mi][ni] = (f32x4){0.f, 0.f, 0.f, 0.f};
        float uacc_s = 0.f, uacc_d = 0.f;
        for (int k0 = 0; k0 < K; k0 += 64) {
#pragma unroll
            for (int i = tid; i < 1024; i += 256) {
                int r = i >> 3, c8 = i & 7;
                int gr = row0 + r;
                uint4 v = make_uint4(0u, 0u, 0u, 0u);
                if (gr < n) v = *(const uint4*)(A + (size_t)gr * K + k0 + c8 * 8);
                *(uint4*)&As[r][c8 * 8] = v;
            }
#pragma unroll
            for (int i = tid; i < BN * 8; i += 256) {
                int r = i >> 3, c8 = i & 7;
                uint4 v = *(const uint4*)(Wb + (size_t)(col0 + r) * K + k0 + c8 * 8);
                *(uint4*)&Ws[r][c8 * 8] = v;
            }
            __syncthreads();
            if (doU) {
                int kb = uhalf * 32;
#pragma unroll
                for (int q = 0; q < 4; q++) {
                    uint4 rw = *(const uint4*)&As[urow][kb + q * 8];
                    int kk = k0 + kb + q * 8;
                    float a[8] = {
                        __uint_as_float(rw.x << 16), __uint_as_float(rw.x & 0xffff0000u),
                        __uint_as_float(rw.y << 16), __uint_as_float(rw.y & 0xffff0000u),
                        __uint_as_float(rw.z << 16), __uint_as_float(rw.z & 0xffff0000u),
                        __uint_as_float(rw.w << 16), __uint_as_float(rw.w & 0xffff0000u)};
#pragma unroll
                    for (int j = 0; j < 8; j++) {
                        uacc_s += a[j] * us[kk + j];
                        uacc_d += a[j] * ud[kk + j];
                    }
                }
            }
#pragma unroll
            for (int kk = 0; kk < 64; kk += 32) {
                bf16x8 bfr[SN];
#pragma unroll
                for (int ni = 0; ni < SN; ni++)
                    bfr[ni] = *(const bf16x8*)&Ws[wc * (BN / 2) + ni * 16 + l15][kk + quad * 8];
#pragma unroll
                for (int mi = 0; mi < 4; mi++) {
                    bf16x8 afr = *(const bf16x8*)&As[wr * 64 + mi * 16 + l15][kk + quad * 8];
#pragma unroll
                    for (int ni = 0; ni < SN; ni++)
                        acc[mi][ni] = __builtin_amdgcn_mfma_f32_16x16x32_bf16(
                            afr, bfr[ni], acc[mi][ni], 0, 0, 0);
                }
            }
            __syncthreads();
        }
        if (doU) {
            float* red = (float*)smem;
            red[tid] = uacc_s;
            red[256 + tid] = uacc_d;
            __syncthreads();
            if (tid < 128) {
                int gr = row0 + tid;
                if (gr < n) {
                    as_[gr] = red[tid] + red[tid + 128];
                    ad_[gr] = red[256 + tid] + red[384 + tid];
                }
            }
        }
        int gc[SN];
#pragma unroll
        for (int ni = 0; ni < SN; ni++) gc[ni] = col0 + wc * (BN / 2) + ni * 16 + l15;
#pragma unroll
        for (int mi = 0; mi < 4; mi++) {
            int gm0 = row0 + wr * 64 + mi * 16 + quad * 4;
#pragma unroll
            for (int ni = 0; ni < SN; ni++) {
#pragma unroll
                for (int r = 0; r < 4; r++) {
                    int gm = gm0 + r;
                    if (gm < n) Cb[(size_t)gm * O + gc[ni]] = f2bf(acc[mi][ni][r]);
                }
            }
        }
        __syncthreads();  // protect LDS before next tile restages
    }
}

// ---------------- GAT aggregation phase: wave per dst node, grid-stride over nodes --------
template <int O>
__device__ void agg_phase(const unsigned short* __restrict__ hl, const float* __restrict__ as_,
                          const float* __restrict__ ad_, const int* __restrict__ rowptr,
                          const int* __restrict__ esrc, const float* __restrict__ bias,
                          unsigned short* __restrict__ hout, int n,
                          const float* __restrict__ usn, const float* __restrict__ udn,
                          float* __restrict__ as_out, float* __restrict__ ad_out, int waveId,
                          int nWaves, int lane) {
    constexpr int C8 = O / 8;
    constexpr int EPW = 64 / C8;
    int sub = lane / C8;
    int c = lane % C8;
    for (int v = waveId; v < n; v += nWaves) {
        int beg = rowptr[v], end = rowptr[v + 1];
        int deg = end - beg;
        float adv = ad_[v];
        float acc[8] = {0.f, 0.f, 0.f, 0.f, 0.f, 0.f, 0.f, 0.f};
        if (deg <= 64) {
            int sreg = v;
            float e = -1e30f;
            if (lane < deg) {
                sreg = esrc[beg + lane];
                float t = as_[sreg] + adv;
                e = (t > 0.f) ? t : 0.2f * t;
            }
            float m = e;
#pragma unroll
            for (int o = 32; o > 0; o >>= 1) m = fmaxf(m, __shfl_xor(m, o));
            float ex = (lane < deg) ? __expf(e - m) : 0.f;
            float sum = ex;
#pragma unroll
            for (int o = 32; o > 0; o >>= 1) sum += __shfl_xor(sum, o);
            float alpha_r = ex / sum;
            for (int j0 = 0; j0 < deg; j0 += EPW) {
                int idx = j0 + sub;
                int cidx = (idx < deg) ? idx : 0;
                float alpha = __shfl(alpha_r, cidx);
                int s2 = __shfl(sreg, cidx);
                if (idx >= deg) alpha = 0.f;
                uint4 raw = ((const uint4*)(hl + (size_t)s2 * O))[c];
                acc[0] += alpha * __uint_as_float(raw.x << 16);
                acc[1] += alpha * __uint_as_float(raw.x & 0xffff0000u);
                acc[2] += alpha * __uint_as_float(raw.y << 16);
                acc[3] += alpha * __uint_as_float(raw.y & 0xffff0000u);
                acc[4] += alpha * __uint_as_float(raw.z << 16);
                acc[5] += alpha * __uint_as_float(raw.z & 0xffff0000u);
                acc[6] += alpha * __uint_as_float(raw.w << 16);
                acc[7] += alpha * __uint_as_float(raw.w & 0xffff0000u);
            }
        } else {
            float mymax = -1e30f;
            for (int j = beg + lane; j < end; j += 64) {
                float e = as_[esrc[j]] + adv;
                e = (e > 0.f) ? e : 0.2f * e;
                mymax = fmaxf(mymax, e);
            }
#pragma unroll
            for (int o = 32; o > 0; o >>= 1) mymax = fmaxf(mymax, __shfl_xor(mymax, o));
            float mysum = 0.f;
            for (int j = beg + lane; j < end; j += 64) {
                float e = as_[esrc[j]] + adv;
                e = (e > 0.f) ? e : 0.2f * e;
                mysum += __expf(e - mymax);
            }
#pragma unroll
            for (int o = 32; o > 0; o >>= 1) mysum += __shfl_xor(mysum, o);
            float invden = 1.f / mysum;
            for (int j0 = beg; j0 < end; j0 += EPW) {
                int j = j0 + sub;
                bool valid = j < end;
                int s = valid ? esrc[j] : v;
                float e = as_[s] + adv;
                e = (e > 0.f) ? e : 0.2f * e;
                float alpha = valid ? __expf(e - mymax) * invden : 0.f;
                uint4 raw = ((const uint4*)(hl + (size_t)s * O))[c];
                acc[0] += alpha * __uint_as_float(raw.x << 16);
                acc[1] += alpha * __uint_as_float(raw.x & 0xffff0000u);
                acc[2] += alpha * __uint_as_float(raw.y << 16);
                acc[3] += alpha * __uint_as_float(raw.y & 0xffff0000u);
                acc[4] += alpha * __uint_as_float(raw.z << 16);
                acc[5] += alpha * __uint_as_float(raw.z & 0xffff0000u);
                acc[6] += alpha * __uint_as_float(raw.w << 16);
                acc[7] += alpha * __uint_as_float(raw.w & 0xffff0000u);
            }
        }
#pragma unroll
        for (int o = C8; o < 64; o <<= 1)
#pragma unroll
            for (int k = 0; k < 8; k++) acc[k] += __shfl_xor(acc[k], o);
        if (sub == 0) {
            float val[8];
#pragma unroll
            for (int k = 0; k < 8; k++) val[k] = fmaxf(acc[k] + bias[c * 8 + k], 0.f);
            if (usn) {
                float ps = 0.f, pd = 0.f;
#pragma unroll
                for (int k = 0; k < 8; k++) {
                    ps += val[k] * usn[c * 8 + k];
                    pd += val[k] * udn[c * 8 + k];
                }
#pragma unroll
                for (int m = 1; m < C8; m <<= 1) {
                    ps += __shfl_xor(ps, m);
                    pd += __shfl_xor(pd, m);
                }
                if (lane == 0) {
                    as_out[v] = ps;
                    ad_out[v] = pd;
                }
            }
            unsigned short ov[8];
#pragma unroll
            for (int k = 0; k < 8; k++) ov[k] = f2bf(val[k]);
            uint4 packed;
            packed.x = (unsigned)ov[0] | ((unsigned)ov[1] << 16);
            packed.y = (unsigned)ov[2] | ((unsigned)ov[3] << 16);
            packed.z = (unsigned)ov[4] | ((unsigned)ov[5] << 16);
            packed.w = (unsigned)ov[6] | ((unsigned)ov[7] << 16);
            ((uint4*)(hout + (size_t)v * O))[c] = packed;
        }
    }
}

// ---------------- the whole pipeline as one cooperative kernel ----------------
__global__ __launch_bounds__(256) void mega_kernel(Params p) {
    cg::grid_group grid = cg::this_grid();
    __shared__ __align__(16) char smem[27648];
    int tid = threadIdx.x;
    int gtid = blockIdx.x * 256 + tid;
    int gthreads = gridDim.x * 256;
    int lane = tid & 63;
    int waveId = gtid >> 6;
    int nWaves = gthreads >> 6;
    int N = p.N, E = p.E, G = p.G;
    int Etot = E + N;

    // ---- phase 0: deg zero, weight cast, graph starts, u vectors, MLP ----
    for (int i = gtid; i < N; i += gthreads) p.deg[i] = 0;
    for (int i = gtid; i < 83968; i += gthreads) {
        float v;
        if (i < 8192) v = p.gw[0][i];
        else if (i < 40960) v = p.gw[1][i - 8192];
        else if (i < 73728) v = p.gw[2][i - 40960];
        else if (i < 81920) v = p.gw[3][i - 73728];
        else v = p.gw[4][i - 81920];
        p.wbAll[i] = f2bf(v);
    }
    for (int g = gtid; g <= G; g += gthreads) {
        if (g == G) {
            p.gstart[G] = N;
        } else {
            int lo = 0, hi = N;
            while (lo < hi) {
                int mid = (lo + hi) >> 1;
                if (p.batch[mid] < g) lo = mid + 1;
                else hi = mid;
            }
            p.gstart[g] = lo;
        }
    }
    // u vectors: one wave per output element (640 of them)
    for (int idx = waveId; idx < 640; idx += nWaves) {
        int l, st, K, O;
        if (idx < 64) { l = 0; st = 0; K = 64; O = 128; }
        else if (idx < 192) { l = 1; st = 64; K = 128; O = 256; }
        else if (idx < 448) { l = 2; st = 192; K = 256; O = 128; }
        else if (idx < 576) { l = 3; st = 448; K = 128; O = 64; }
        else { l = 4; st = 576; K = 64; O = 32; }
        int k = idx - st;
        float us = 0.f, ud = 0.f;
        for (int o = lane; o < O; o += 64) {
            float w = p.gw[l][o * K + k];
            us += w * p.gas[l][o];
            ud += w * p.gad[l][o];
        }
#pragma unroll
        for (int o = 32; o > 0; o >>= 1) {
            us += __shfl_xor(us, o);
            ud += __shfl_xor(ud, o);
        }
        if (lane == 0) {
            p.uAll[idx] = us;
            p.uAll[640 + idx] = ud;
        }
    }
    // MLP: weights in VGPRs (loaded once per wave), readlane broadcast, no LDS/SMEM
    {
        float vw1 = p.w1[lane & 15], vb1 = p.b1[lane & 15];
        float vb2 = p.b2[lane & 31], vb3 = p.b3[lane];
        float vw2[8], vw3[32];
#pragma unroll
        for (int j = 0; j < 8; j++) vw2[j] = p.w2[j * 64 + lane];
#pragma unroll
        for (int j = 0; j < 32; j++) vw3[j] = p.w3[j * 64 + lane];
        for (int base = waveId * 64; base < N; base += nWaves * 64) {
            int node = base + lane;
            float xv = (node < N) ? p.x[node] : 0.f;
            float t1[16], t2[32];
#pragma unroll
            for (int i = 0; i < 16; i++) t1[i] = fmaxf(RL(vw1, i) * xv + RL(vb1, i), 0.f);
#pragma unroll
            for (int o = 0; o < 32; o++) {
                float a = RL(vb2, o);
#pragma unroll
                for (int i = 0; i < 16; i++) {
                    int flat = o * 16 + i;
                    a += RL(vw2[flat >> 6], flat & 63) * t1[i];
                }
                t2[o] = fmaxf(a, 0.f);
            }
            if (node < N) {
                uint4* gp = (uint4*)(p.actA + (size_t)node * 64);
#pragma unroll
                for (int cc = 0; cc < 8; cc++) {
                    float av[8];
#pragma unroll
                    for (int j = 0; j < 8; j++) {
                        int o = cc * 8 + j;
                        float a = RL(vb3, o);
#pragma unroll
                        for (int i = 0; i < 32; i++) {
                            int flat = o * 32 + i;
                            a += RL(vw3[flat >> 6], flat & 63) * t2[i];
                        }
                        av[j] = fmaxf(a, 0.f);
                    }
                    unsigned wv[4];
#pragma unroll
                    for (int pp = 0; pp < 4; pp++)
                        wv[pp] = (unsigned)f2bf(av[2 * pp]) |
                                 ((unsigned)f2bf(av[2 * pp + 1]) << 16);
                    gp[cc] = make_uint4(wv[0], wv[1], wv[2], wv[3]);
                }
            }
        }
    }
    grid.sync();

    // ---- phase 1: degree histogram ----
    for (int e = gtid; e < Etot; e += gthreads) {
        int d = (e < E) ? p.ei[E + e] : (e - E);
        atomicAdd(&p.deg[d], 1);
    }
    grid.sync();

    // ---- phase 2: per-1024-chunk sums ----
    int nb = (N + 1023) / 1024;
    {
        int* sdata = (int*)smem;
        for (int vb = blockIdx.x; vb < nb; vb += gridDim.x) {
            int base = vb * 1024 + tid * 4;
            int s = 0;
            for (int i = 0; i < 4; i++) {
                int g = base + i;
                if (g < N) s += p.deg[g];
            }
            sdata[tid] = s;
            __syncthreads();
            for (int off = 128; off > 0; off >>= 1) {
                if (tid < off) sdata[tid] += sdata[tid + off];
                __syncthreads();
            }
            if (tid == 0) p.bsums[vb] = sdata[0];
            __syncthreads();
        }
    }
    grid.sync();

    // ---- phase 3: rowptr/cursor (inline bsums prefix, nb <= 256) ----
    {
        int* sdata = (int*)smem;
        for (int vb = blockIdx.x; vb < nb; vb += gridDim.x) {
            sdata[tid] = (tid < vb && tid < nb) ? p.bsums[tid] : 0;
            __syncthreads();
            for (int off = 128; off > 0; off >>= 1) {
                if (tid < off) sdata[tid] += sdata[tid + off];
                __syncthreads();
            }
            int base0 = sdata[0];
            __syncthreads();
            int gbase = vb * 1024 + tid * 4;
            int vv[4];
            int s = 0;
            for (int i = 0; i < 4; i++) {
                int g = gbase + i;
                vv[i] = (g < N) ? p.deg[g] : 0;
                s += vv[i];
            }
            sdata[tid] = s;
            __syncthreads();
            for (int off = 1; off < 256; off <<= 1) {
                int t2 = (tid >= off) ? sdata[tid - off] : 0;
                __syncthreads();
                sdata[tid] += t2;
                __syncthreads();
            }
            int excl = sdata[tid] - s + base0;
            for (int i = 0; i < 4; i++) {
                int g = gbase + i;
                if (g < N) {
                    p.rowptr[g] = excl;
                    p.cursor[g] = excl;
                }
                excl += vv[i];
            }
            if (vb == nb - 1 && tid == 255) p.rowptr[N] = base0 + sdata[255];
            __syncthreads();
        }
    }
    grid.sync();

    // ---- phase 4: scatter edges into CSR ----
    for (int e = gtid; e < Etot; e += gthreads) {
        int s, d;
        if (e < E) { s = p.ei[e]; d = p.ei[E + e]; }
        else { s = e - E; d = e - E; }
        int pos = atomicAdd(&p.cursor[d], 1);
        p.esrc[pos] = s;
    }
    grid.sync();

    // ---- phases 5..14: five GAT layers ----
    float* lgA = p.logit0;  // layer-l logits
    float* lgB = p.logit1;
    // layer 0: K=64, O=128 (gemm emits logits via u0)
    gemm_phase<64>(p.actA, p.wbAll + 0, p.actB, p.uAll + 0, p.uAll + 640, lgA, lgA + N, N, 64,
                   128, smem);
    grid.sync();
    agg_phase<128>(p.actB, lgA, lgA + N, p.rowptr, p.esrc, p.gb[0], p.actA, N, p.uAll + 64,
                   p.uAll + 704, lgB, lgB + N, waveId, nWaves, lane);
    grid.sync();
    // layer 1: K=128, O=256
    gemm_phase<64>(p.actA, p.wbAll + 8192, p.actB, nullptr, nullptr, nullptr, nullptr, N, 128,
                   256, smem);
    grid.sync();
    agg_phase<256>(p.actB, lgB, lgB + N, p.rowptr, p.esrc, p.gb[1], p.actA, N, p.uAll + 192,
                   p.uAll + 832, lgA, lgA + N, waveId, nWaves, lane);
    grid.sync();
    // layer 2: K=256, O=128
    gemm_phase<64>(p.actA, p.wbAll + 40960, p.actB, nullptr, nullptr, nullptr, nullptr, N, 256,
                   128, smem);
    grid.sync();
    agg_phase<128>(p.actB, lgA, lgA + N, p.rowptr, p.esrc, p.gb[2], p.actA, N, p.uAll + 448,
                   p.uAll + 1088, lgB, lgB + N, waveId, nWaves, lane);
    grid.sync();
    // layer 3: K=128, O=64
    gemm_phase<64>(p.actA, p.wbAll + 73728, p.actB, nullptr, nullptr, nullptr, nullptr, N, 128,
                   64, smem);
    grid.sync();
    agg_phase<64>(p.actB, lgB, lgB + N, p.rowptr, p.esrc, p.gb[3], p.actA, N, p.uAll + 576,
                  p.uAll + 1216, lgA, lgA + N, waveId, nWaves, lane);
    grid.sync();
    // layer 4: K=64, O=32
    gemm_phase<32>(p.actA, p.wbAll + 81920, p.actB, nullptr, nullptr, nullptr, nullptr, N, 64,
                   32, smem);
    grid.sync();
    agg_phase<32>(p.actB, lgA, lgA + N, p.rowptr, p.esrc, p.gb[4], p.actA, N, nullptr, nullptr,
                  nullptr, nullptr, waveId, nWaves, lane);
    grid.sync();

    // ---- phase 15: mean pool + linear + sigmoid ----
    {
        float* red = (float*)smem;  // 8x33
        int nodeLane = tid >> 5, f = tid & 31;
        for (int g = blockIdx.x; g < G; g += gridDim.x) {
            int beg = p.gstart[g], end = p.gstart[g + 1];
            float acc = 0.f;
            for (int v = beg + nodeLane; v < end; v += 8)
                acc += bf2f(p.actA[(size_t)v * 32 + f]);
            red[nodeLane * 33 + f] = acc;
            __syncthreads();
            if (tid < 32) {
                float s = 0.f;
#pragma unroll
                for (int i = 0; i < 8; i++) s += red[i * 33 + f];
                float inv = 1.f / fmaxf((float)(end - beg), 1.f);
                float val = s * inv * p.lw[f];
#pragma unroll
                for (int o = 16; o > 0; o >>= 1) val += __shfl_xor(val, o);
                if (f == 0) p.out[g] = 1.f / (1.f + __expf(-(val + p.lb[0])));
            }
            __syncthreads();
        }
    }
}

extern "C" void kernel_launch(void* const* d_in, const int* in_sizes, int n_in, void* d_out,
                              int out_size, void* d_ws, size_t ws_size, hipStream_t stream) {
    Params p;
    p.x = (const float*)d_in[0];
    p.ei = (const int*)d_in[1];
    p.batch = (const int*)d_in[2];
    p.w1 = (const float*)d_in[3];
    p.b1 = (const float*)d_in[4];
    p.w2 = (const float*)d_in[5];
    p.b2 = (const float*)d_in[6];
    p.w3 = (const float*)d_in[7];
    p.b3 = (const float*)d_in[8];
    for (int l = 0; l < 5; l++) {
        p.gw[l] = (const float*)d_in[9 + l * 4 + 0];
        p.gas[l] = (const float*)d_in[9 + l * 4 + 1];
        p.gad[l] = (const float*)d_in[9 + l * 4 + 2];
        p.gb[l] = (const float*)d_in[9 + l * 4 + 3];
    }
    p.lw = (const float*)d_in[29];
    p.lb = (const float*)d_in[30];
    p.out = (float*)d_out;
    p.N = in_sizes[0];
    p.E = in_sizes[1] / 2;
    p.G = out_size;
    int N = p.N, E = p.E, G = p.G;
    int Etot = E + N;

    char* ws = (char*)d_ws;
    size_t off = 0;
    auto alloc = [&](size_t bytes) -> void* {
        void* ptr = ws + off;
        off = (off + bytes + 255) & ~(size_t)255;
        return ptr;
    };
    p.actA = (unsigned short*)alloc((size_t)N * 256 * 2);
    p.actB = (unsigned short*)alloc((size_t)N * 256 * 2);
    p.logit0 = (float*)alloc((size_t)N * 8);
    p.logit1 = (float*)alloc((size_t)N * 8);
    p.deg = (int*)alloc((size_t)N * 4);
    p.rowptr = (int*)alloc((size_t)(N + 1) * 4);
    p.cursor = (int*)alloc((size_t)(N + 1) * 4);
    p.esrc = (int*)alloc((size_t)Etot * 4);
    p.bsums = (int*)alloc(4096);
    p.gstart = (int*)alloc((size_t)(G + 1) * 4);
    p.wbAll = (unsigned short*)alloc((size_t)83968 * 2);
    p.uAll = (float*)alloc((size_t)1280 * 4);
    (void)ws_size;
    (void)n_in;

    // size the cooperative grid to full co-residency
    int nbpc = 0;
    hipOccupancyMaxActiveBlocksPerMultiprocessor(&nbpc, (const void*)mega_kernel, 256, 0);
    if (nbpc < 1) nbpc = 1;
    int dev = 0;
    hipGetDevice(&dev);
    int numCU = 256;
    hipDeviceGetAttribute(&numCU, hipDeviceAttributeMultiprocessorCount, dev);
    int gridBlocks = nbpc * numCU;

    void* args[] = {&p};
    hipLaunchCooperativeKernel((const void*)mega_kernel, dim3(gridBlocks), dim3(256), args, 0,
                               stream);
}

// Round 11
// 712.367 us; speedup vs baseline: 2.7821x; 2.7821x over previous
//
#include <hip/hip_runtime.h>
#include <math.h>

typedef __attribute__((ext_vector_type(8))) __bf16 bf16x8;
typedef __attribute__((ext_vector_type(4))) float f32x4;

__device__ inline unsigned short f2bf(float f) {  // RNE
    unsigned int i = __float_as_uint(f);
    unsigned int r = i + 0x7fffu + ((i >> 16) & 1u);
    return (unsigned short)(r >> 16);
}
__device__ inline float bf2f(unsigned short u) {
    return __uint_as_float(((unsigned int)u) << 16);
}
#define RL(v, l) __uint_as_float(__builtin_amdgcn_readlane(__float_as_uint(v), (l)))

#define F2BF_B 329  // ceil(83968/256)
#define U_B 3       // ceil(640/256)

// ---------------- MLP: dedicated kernel, weights in VGPRs + readlane broadcast ------------
// __launch_bounds__(256,2): 2 blocks/CU floor -> up to ~256 VGPR/wave, no spill (R9 bug:
// merged-prelude allocator chose 48 VGPR and spilled the weight arrays to scratch).
__global__ __launch_bounds__(256, 2) void mlp_kernel(
    const float* __restrict__ x,
    const float* __restrict__ w1, const float* __restrict__ b1,
    const float* __restrict__ w2, const float* __restrict__ b2,
    const float* __restrict__ w3, const float* __restrict__ b3,
    unsigned short* __restrict__ h0, int n) {
    int tid = threadIdx.x;
    int lane = tid & 63;
    int node = blockIdx.x * 256 + tid;
    // no early return before loads: tail lanes must populate readlane sources
    float vw1 = w1[lane & 15], vb1 = b1[lane & 15];
    float vb2 = b2[lane & 31], vb3 = b3[lane];
    float vw2[8], vw3[32];
#pragma unroll
    for (int j = 0; j < 8; j++) vw2[j] = w2[j * 64 + lane];
#pragma unroll
    for (int j = 0; j < 32; j++) vw3[j] = w3[j * 64 + lane];
    float xv = (node < n) ? x[node] : 0.f;
    float t1[16], t2[32];
#pragma unroll
    for (int i = 0; i < 16; i++) t1[i] = fmaxf(RL(vw1, i) * xv + RL(vb1, i), 0.f);
#pragma unroll
    for (int o = 0; o < 32; o++) {
        float a = RL(vb2, o);
#pragma unroll
        for (int i = 0; i < 16; i++) {
            int flat = o * 16 + i;
            a += RL(vw2[flat >> 6], flat & 63) * t1[i];
        }
        t2[o] = fmaxf(a, 0.f);
    }
    if (node >= n) return;
    uint4* gp = (uint4*)(h0 + (size_t)node * 64);
#pragma unroll
    for (int c = 0; c < 8; c++) {
        float av[8];
#pragma unroll
        for (int j = 0; j < 8; j++) {
            int o = c * 8 + j;
            float a = RL(vb3, o);
#pragma unroll
            for (int i = 0; i < 32; i++) {
                int flat = o * 32 + i;
                a += RL(vw3[flat >> 6], flat & 63) * t2[i];
            }
            av[j] = fmaxf(a, 0.f);
        }
        unsigned wv[4];
#pragma unroll
        for (int p = 0; p < 4; p++)
            wv[p] = (unsigned)f2bf(av[2 * p]) | ((unsigned)f2bf(av[2 * p + 1]) << 16);
        gp[c] = make_uint4(wv[0], wv[1], wv[2], wv[3]);
    }
}

// ---------------- prelude: weight-cast + graph starts + u vectors + degree hist ----------
__global__ __launch_bounds__(256) void prelude_kernel(
    const float* __restrict__ g0, const float* __restrict__ g1, const float* __restrict__ g2,
    const float* __restrict__ g3, const float* __restrict__ g4,
    unsigned short* __restrict__ wbAll,
    const float* __restrict__ s0, const float* __restrict__ s1, const float* __restrict__ s2,
    const float* __restrict__ s3, const float* __restrict__ s4,
    const float* __restrict__ d0, const float* __restrict__ d1, const float* __restrict__ d2,
    const float* __restrict__ d3, const float* __restrict__ d4,
    float* __restrict__ uAll,
    const int* __restrict__ batch, int* __restrict__ gstart, int G,
    const int* __restrict__ dst, int* __restrict__ deg, int E, int n, int gsB) {
    int b = blockIdx.x;
    int tid = threadIdx.x;
    if (b < F2BF_B) {
        int i = b * 256 + tid;
        // weight segment offsets: 0, 8192, 40960, 73728, 81920, end 83968
        float v;
        if (i < 8192) v = g0[i];
        else if (i < 40960) v = g1[i - 8192];
        else if (i < 73728) v = g2[i - 40960];
        else if (i < 81920) v = g3[i - 73728];
        else if (i < 83968) v = g4[i - 81920];
        else return;
        wbAll[i] = f2bf(v);
    } else if (b < F2BF_B + gsB) {
        int g = (b - F2BF_B) * 256 + tid;
        if (g > G) return;
        if (g == G) { gstart[G] = n; return; }
        int lo = 0, hi = n;
        while (lo < hi) {
            int mid = (lo + hi) >> 1;
            if (batch[mid] < g) lo = mid + 1;
            else hi = mid;
        }
        gstart[g] = lo;
    } else if (b < F2BF_B + gsB + U_B) {
        // u_s[k] = sum_o W[o][k]*a_s[o]; layers packed at {0,64,192,448,576}, total 640
        int idx = (b - F2BF_B - gsB) * 256 + tid;
        if (idx >= 640) return;
        int l, st, K, O;
        if (idx < 64) { l = 0; st = 0; K = 64; O = 128; }
        else if (idx < 192) { l = 1; st = 64; K = 128; O = 256; }
        else if (idx < 448) { l = 2; st = 192; K = 256; O = 128; }
        else if (idx < 576) { l = 3; st = 448; K = 128; O = 64; }
        else { l = 4; st = 576; K = 64; O = 32; }
        const float* W = (l == 0) ? g0 : (l == 1) ? g1 : (l == 2) ? g2 : (l == 3) ? g3 : g4;
        const float* as = (l == 0) ? s0 : (l == 1) ? s1 : (l == 2) ? s2 : (l == 3) ? s3 : s4;
        const float* ad = (l == 0) ? d0 : (l == 1) ? d1 : (l == 2) ? d2 : (l == 3) ? d3 : d4;
        int k = idx - st;
        float us = 0.f, ud = 0.f;
        for (int o = 0; o < O; o++) {
            float w = W[o * K + k];
            us += w * as[o];
            ud += w * ad[o];
        }
        uAll[idx] = us;
        uAll[640 + idx] = ud;
    } else {
        int e = (b - F2BF_B - gsB - U_B) * 256 + tid;
        if (e >= E + n) return;
        int d = (e < E) ? dst[e] : (e - E);
        atomicAdd(&deg[d], 1);
    }
}

// ---------------- bf16 MFMA GEMM, 128xBN tile, BK=64 ----------------
// If us != null (layer 0 only): col0==0 blocks also emit as_[r] = A[r,:].us, ad_ likewise.
template <int BN>
__global__ __launch_bounds__(256) void gemm_mfma(
    const unsigned short* __restrict__ A, const unsigned short* __restrict__ Wb,
    unsigned short* __restrict__ Cb,
    const float* __restrict__ us, const float* __restrict__ ud,
    float* __restrict__ as_, float* __restrict__ ad_, int n, int K, int O) {
    constexpr int SN = BN / 32;
    __shared__ unsigned short As[128][72];  // +8 pad: frag reads <=2-way banks (free)
    __shared__ unsigned short Ws[BN][72];
    int tid = threadIdx.x;
    int row0 = blockIdx.x * 128, col0 = blockIdx.y * BN;
    int w = tid >> 6, lane = tid & 63;
    int wr = w >> 1, wc = w & 1;
    int quad = lane >> 4, l15 = lane & 15;
    f32x4 acc[4][SN];
#pragma unroll
    for (int mi = 0; mi < 4; mi++)
#pragma unroll
        for (int ni = 0; ni < SN; ni++) acc[mi][ni] = (f32x4){0.f, 0.f, 0.f, 0.f};
    float uacc_s = 0.f, uacc_d = 0.f;
    int urow = tid & 127, uhalf = tid >> 7;
    bool doU = (us != nullptr) && (col0 == 0);

    for (int k0 = 0; k0 < K; k0 += 64) {
#pragma unroll
        for (int i = tid; i < 1024; i += 256) {
            int r = i >> 3, c8 = i & 7;
            int gr = row0 + r;
            uint4 v = make_uint4(0u, 0u, 0u, 0u);
            if (gr < n) v = *(const uint4*)(A + (size_t)gr * K + k0 + c8 * 8);
            *(uint4*)&As[r][c8 * 8] = v;
        }
#pragma unroll
        for (int i = tid; i < BN * 8; i += 256) {
            int r = i >> 3, c8 = i & 7;
            uint4 v = *(const uint4*)(Wb + (size_t)(col0 + r) * K + k0 + c8 * 8);
            *(uint4*)&Ws[r][c8 * 8] = v;
        }
        __syncthreads();
        if (doU) {
            int kb = uhalf * 32;
#pragma unroll
            for (int q = 0; q < 4; q++) {
                uint4 rw = *(const uint4*)&As[urow][kb + q * 8];
                int kk = k0 + kb + q * 8;
                float a[8] = {__uint_as_float(rw.x << 16), __uint_as_float(rw.x & 0xffff0000u),
                              __uint_as_float(rw.y << 16), __uint_as_float(rw.y & 0xffff0000u),
                              __uint_as_float(rw.z << 16), __uint_as_float(rw.z & 0xffff0000u),
                              __uint_as_float(rw.w << 16), __uint_as_float(rw.w & 0xffff0000u)};
#pragma unroll
                for (int j = 0; j < 8; j++) {
                    uacc_s += a[j] * us[kk + j];
                    uacc_d += a[j] * ud[kk + j];
                }
            }
        }
#pragma unroll
        for (int kk = 0; kk < 64; kk += 32) {
            bf16x8 bfr[SN];
#pragma unroll
            for (int ni = 0; ni < SN; ni++)
                bfr[ni] = *(const bf16x8*)&Ws[wc * (BN / 2) + ni * 16 + l15][kk + quad * 8];
#pragma unroll
            for (int mi = 0; mi < 4; mi++) {
                bf16x8 afr = *(const bf16x8*)&As[wr * 64 + mi * 16 + l15][kk + quad * 8];
#pragma unroll
                for (int ni = 0; ni < SN; ni++)
                    acc[mi][ni] = __builtin_amdgcn_mfma_f32_16x16x32_bf16(afr, bfr[ni],
                                                                          acc[mi][ni], 0, 0, 0);
            }
        }
        __syncthreads();
    }
    if (doU) {
        float* red = (float*)&As[0][0];
        red[tid] = uacc_s;
        red[256 + tid] = uacc_d;
        __syncthreads();
        if (tid < 128) {
            int gr = row0 + tid;
            if (gr < n) {
                as_[gr] = red[tid] + red[tid + 128];
                ad_[gr] = red[256 + tid] + red[384 + tid];
            }
        }
    }
    int gc[SN];
#pragma unroll
    for (int ni = 0; ni < SN; ni++) gc[ni] = col0 + wc * (BN / 2) + ni * 16 + l15;
#pragma unroll
    for (int mi = 0; mi < 4; mi++) {
        int gm0 = row0 + wr * 64 + mi * 16 + quad * 4;
#pragma unroll
        for (int ni = 0; ni < SN; ni++) {
#pragma unroll
            for (int r = 0; r < 4; r++) {
                int gm = gm0 + r;
                if (gm < n) Cb[(size_t)gm * O + gc[ni]] = f2bf(acc[mi][ni][r]);
            }
        }
    }
}

// ---------------- scan_write: one dispatch — each block sums its own prefix base ----------
__global__ void scan_write(const int* __restrict__ deg, int* __restrict__ rowptr,
                           int* __restrict__ cursor, int n) {
    __shared__ int sdata[256];
    int tid = threadIdx.x;
    int limit = blockIdx.x * 1024;  // base = sum(deg[0..limit))
    int s0 = 0;
    for (int i = tid; i < limit; i += 256) s0 += deg[i];
    sdata[tid] = s0;
    __syncthreads();
    for (int off = 128; off > 0; off >>= 1) {
        if (tid < off) sdata[tid] += sdata[tid + off];
        __syncthreads();
    }
    int base = sdata[0];
    __syncthreads();
    int gbase = limit + tid * 4;
    int v[4];
    int s = 0;
    for (int i = 0; i < 4; i++) {
        int g = gbase + i;
        v[i] = (g < n) ? deg[g] : 0;
        s += v[i];
    }
    sdata[tid] = s;
    __syncthreads();
    for (int off = 1; off < 256; off <<= 1) {  // inclusive Hillis-Steele
        int t = (tid >= off) ? sdata[tid - off] : 0;
        __syncthreads();
        sdata[tid] += t;
        __syncthreads();
    }
    int excl = sdata[tid] - s + base;
    for (int i = 0; i < 4; i++) {
        int g = gbase + i;
        if (g < n) { rowptr[g] = excl; cursor[g] = excl; }
        excl += v[i];
    }
    if (blockIdx.x == gridDim.x - 1 && tid == 255) rowptr[n] = base + sdata[255];
}

__global__ void scatter_kernel(const int* __restrict__ esrc_in, const int* __restrict__ edst_in,
                               int* __restrict__ cursor, int* __restrict__ esrc, int E, int n) {
    int e = blockIdx.x * 256 + threadIdx.x;
    if (e >= E + n) return;
    int s, d;
    if (e < E) { s = esrc_in[e]; d = edst_in[e]; }
    else { s = e - E; d = e - E; }
    int pos = atomicAdd(&cursor[d], 1);
    esrc[pos] = s;
}

// ---------------- GAT aggregation: one wave per dst node, bf16 features ----------------
// Epilogue also computes NEXT layer's alpha logits (as_/ad_ ping-pong; usn==null last layer).
template <int O>
__global__ __launch_bounds__(256) void gat_aggregate(
    const unsigned short* __restrict__ hl, const float* __restrict__ as_,
    const float* __restrict__ ad_, const int* __restrict__ rowptr,
    const int* __restrict__ esrc, const float* __restrict__ bias,
    unsigned short* __restrict__ hout, int n,
    const float* __restrict__ usn, const float* __restrict__ udn,
    float* __restrict__ as_out, float* __restrict__ ad_out) {
    constexpr int C8 = O / 8;
    constexpr int EPW = 64 / C8;
    int v = blockIdx.x * 4 + (threadIdx.x >> 6);
    int lane = threadIdx.x & 63;
    if (v >= n) return;
    int beg = rowptr[v], end = rowptr[v + 1];
    int deg = end - beg;
    float adv = ad_[v];
    int sub = lane / C8;
    int c = lane % C8;
    float acc[8] = {0.f, 0.f, 0.f, 0.f, 0.f, 0.f, 0.f, 0.f};
    if (deg <= 64) {
        int sreg = v;
        float e = -1e30f;
        if (lane < deg) {
            sreg = esrc[beg + lane];
            float t = as_[sreg] + adv;
            e = (t > 0.f) ? t : 0.2f * t;
        }
        float m = e;
#pragma unroll
        for (int o = 32; o > 0; o >>= 1) m = fmaxf(m, __shfl_xor(m, o));
        float ex = (lane < deg) ? __expf(e - m) : 0.f;
        float sum = ex;
#pragma unroll
        for (int o = 32; o > 0; o >>= 1) sum += __shfl_xor(sum, o);
        float alpha_r = ex / sum;
        for (int j0 = 0; j0 < deg; j0 += EPW) {
            int idx = j0 + sub;
            int cidx = (idx < deg) ? idx : 0;
            float alpha = __shfl(alpha_r, cidx);
            int s2 = __shfl(sreg, cidx);
            if (idx >= deg) alpha = 0.f;
            uint4 raw = ((const uint4*)(hl + (size_t)s2 * O))[c];
            acc[0] += alpha * __uint_as_float(raw.x << 16);
            acc[1] += alpha * __uint_as_float(raw.x & 0xffff0000u);
            acc[2] += alpha * __uint_as_float(raw.y << 16);
            acc[3] += alpha * __uint_as_float(raw.y & 0xffff0000u);
            acc[4] += alpha * __uint_as_float(raw.z << 16);
            acc[5] += alpha * __uint_as_float(raw.z & 0xffff0000u);
            acc[6] += alpha * __uint_as_float(raw.w << 16);
            acc[7] += alpha * __uint_as_float(raw.w & 0xffff0000u);
        }
    } else {
        float mymax = -1e30f;
        for (int j = beg + lane; j < end; j += 64) {
            float e = as_[esrc[j]] + adv;
            e = (e > 0.f) ? e : 0.2f * e;
            mymax = fmaxf(mymax, e);
        }
#pragma unroll
        for (int o = 32; o > 0; o >>= 1) mymax = fmaxf(mymax, __shfl_xor(mymax, o));
        float mysum = 0.f;
        for (int j = beg + lane; j < end; j += 64) {
            float e = as_[esrc[j]] + adv;
            e = (e > 0.f) ? e : 0.2f * e;
            mysum += __expf(e - mymax);
        }
#pragma unroll
        for (int o = 32; o > 0; o >>= 1) mysum += __shfl_xor(mysum, o);
        float invden = 1.f / mysum;
        for (int j0 = beg; j0 < end; j0 += EPW) {
            int j = j0 + sub;
            bool valid = j < end;
            int s = valid ? esrc[j] : v;
            float e = as_[s] + adv;
            e = (e > 0.f) ? e : 0.2f * e;
            float alpha = valid ? __expf(e - mymax) * invden : 0.f;
            uint4 raw = ((const uint4*)(hl + (size_t)s * O))[c];
            acc[0] += alpha * __uint_as_float(raw.x << 16);
            acc[1] += alpha * __uint_as_float(raw.x & 0xffff0000u);
            acc[2] += alpha * __uint_as_float(raw.y << 16);
            acc[3] += alpha * __uint_as_float(raw.y & 0xffff0000u);
            acc[4] += alpha * __uint_as_float(raw.z << 16);
            acc[5] += alpha * __uint_as_float(raw.z & 0xffff0000u);
            acc[6] += alpha * __uint_as_float(raw.w << 16);
            acc[7] += alpha * __uint_as_float(raw.w & 0xffff0000u);
        }
    }
#pragma unroll
    for (int o = C8; o < 64; o <<= 1)
#pragma unroll
        for (int k = 0; k < 8; k++) acc[k] += __shfl_xor(acc[k], o);
    if (sub == 0) {
        float val[8];
#pragma unroll
        for (int k = 0; k < 8; k++) val[k] = fmaxf(acc[k] + bias[c * 8 + k], 0.f);
        if (usn) {
            float ps = 0.f, pd = 0.f;
#pragma unroll
            for (int k = 0; k < 8; k++) {
                ps += val[k] * usn[c * 8 + k];
                pd += val[k] * udn[c * 8 + k];
            }
#pragma unroll
            for (int m = 1; m < C8; m <<= 1) {
                ps += __shfl_xor(ps, m);
                pd += __shfl_xor(pd, m);
            }
            if (lane == 0) {
                as_out[v] = ps;
                ad_out[v] = pd;
            }
        }
        unsigned short ov[8];
#pragma unroll
        for (int k = 0; k < 8; k++) ov[k] = f2bf(val[k]);
        uint4 packed;
        packed.x = (unsigned)ov[0] | ((unsigned)ov[1] << 16);
        packed.y = (unsigned)ov[2] | ((unsigned)ov[3] << 16);
        packed.z = (unsigned)ov[4] | ((unsigned)ov[5] << 16);
        packed.w = (unsigned)ov[6] | ((unsigned)ov[7] << 16);
        ((uint4*)(hout + (size_t)v * O))[c] = packed;
    }
}

// ---------------- fused mean-pool + linear + sigmoid: one block per graph ----------------
__global__ __launch_bounds__(256) void pool_final_kernel(
    const unsigned short* __restrict__ h, const int* __restrict__ start,
    const float* __restrict__ lw, const float* __restrict__ lb,
    float* __restrict__ out, int G) {
    __shared__ float red[8][33];
    int g = blockIdx.x;
    if (g >= G) return;
    int beg = start[g], end = start[g + 1];
    int tid = threadIdx.x;
    int nodeLane = tid >> 5, f = tid & 31;
    float acc = 0.f;
    for (int v = beg + nodeLane; v < end; v += 8)
        acc += bf2f(h[(size_t)v * 32 + f]);
    red[nodeLane][f] = acc;
    __syncthreads();
    if (tid < 32) {
        float s = 0.f;
#pragma unroll
        for (int i = 0; i < 8; i++) s += red[i][f];
        float inv = 1.f / fmaxf((float)(end - beg), 1.f);
        float val = s * inv * lw[f];
#pragma unroll
        for (int o = 16; o > 0; o >>= 1) val += __shfl_xor(val, o);
        if (f == 0) out[g] = 1.f / (1.f + __expf(-(val + lb[0])));
    }
}

extern "C" void kernel_launch(void* const* d_in, const int* in_sizes, int n_in,
                              void* d_out, int out_size, void* d_ws, size_t ws_size,
                              hipStream_t stream) {
    const float* x = (const float*)d_in[0];
    const int* ei = (const int*)d_in[1];
    const int* batch = (const int*)d_in[2];
    const float* w1 = (const float*)d_in[3];
    const float* b1 = (const float*)d_in[4];
    const float* w2 = (const float*)d_in[5];
    const float* b2 = (const float*)d_in[6];
    const float* w3 = (const float*)d_in[7];
    const float* b3 = (const float*)d_in[8];
    const float* gw[5];
    const float* gas[5];
    const float* gad[5];
    const float* gb[5];
    for (int l = 0; l < 5; l++) {
        gw[l] = (const float*)d_in[9 + l * 4 + 0];
        gas[l] = (const float*)d_in[9 + l * 4 + 1];
        gad[l] = (const float*)d_in[9 + l * 4 + 2];
        gb[l] = (const float*)d_in[9 + l * 4 + 3];
    }
    const float* lw = (const float*)d_in[29];
    const float* lb = (const float*)d_in[30];
    float* out = (float*)d_out;

    int N = in_sizes[0];
    int E = in_sizes[1] / 2;
    int G = out_size;
    int Etot = E + N;

    char* ws = (char*)d_ws;
    size_t off = 0;
    auto alloc = [&](size_t bytes) -> void* {
        void* p = ws + off;
        off = (off + bytes + 255) & ~(size_t)255;
        return p;
    };
    unsigned short* actA = (unsigned short*)alloc((size_t)N * 256 * 2);
    unsigned short* actB = (unsigned short*)alloc((size_t)N * 256 * 2);
    float* logit0 = (float*)alloc((size_t)N * 8);  // as|ad ping
    float* logit1 = (float*)alloc((size_t)N * 8);  // as|ad pong
    int* deg = (int*)alloc((size_t)N * 4);
    int* rowptr = (int*)alloc((size_t)(N + 1) * 4);
    int* cursor = (int*)alloc((size_t)(N + 1) * 4);
    int* esrc = (int*)alloc((size_t)Etot * 4);
    int* gstart = (int*)alloc((size_t)(G + 1) * 4);
    unsigned short* wbAll = (unsigned short*)alloc((size_t)83968 * 2);
    float* uAll = (float*)alloc((size_t)1280 * 4);
    const int woff[5] = {0, 8192, 40960, 73728, 81920};
    const int uoff[5] = {0, 64, 192, 448, 576};
    unsigned short* wb[5];
    for (int l = 0; l < 5; l++) wb[l] = wbAll + woff[l];
    (void)ws_size;
    (void)n_in;

    // 0. zero deg
    hipMemsetAsync(deg, 0, (size_t)N * 4, stream);

    // 1. MLP (dedicated — full register budget) + prelude (cast/gstart/u/hist)
    mlp_kernel<<<(N + 255) / 256, 256, 0, stream>>>(x, w1, b1, w2, b2, w3, b3, actA, N);
    int gsB = (G + 1 + 255) / 256;
    int histB = (Etot + 255) / 256;
    prelude_kernel<<<F2BF_B + gsB + U_B + histB, 256, 0, stream>>>(
        gw[0], gw[1], gw[2], gw[3], gw[4], wbAll,
        gas[0], gas[1], gas[2], gas[3], gas[4], gad[0], gad[1], gad[2], gad[3], gad[4], uAll,
        batch, gstart, G, ei + E, deg, E, N, gsB);

    // 2. CSR: single-dispatch scan (self-computed base) + scatter
    int nb = (N + 1023) / 1024;
    scan_write<<<nb, 256, 0, stream>>>(deg, rowptr, cursor, N);
    scatter_kernel<<<(Etot + 255) / 256, 256, 0, stream>>>(ei, ei + E, cursor, esrc, E, N);

    // 3. five GAT layers (logits ping-pong; gemm0 emits layer-0 logits, agg emits next)
    int aggBlocks = (N + 3) / 4;
    int gx = (N + 127) / 128;
    const int Ks[5] = {64, 128, 256, 128, 64};
    const int Os[5] = {128, 256, 128, 64, 32};
    for (int l = 0; l < 5; l++) {
        int K = Ks[l], O = Os[l];
        float* lg = (l & 1) ? logit1 : logit0;
        float* lgn = (l & 1) ? logit0 : logit1;
        const float* gus = (l == 0) ? uAll + uoff[0] : nullptr;
        const float* gud = (l == 0) ? uAll + 640 + uoff[0] : nullptr;
        const float* usn = (l < 4) ? uAll + uoff[l + 1] : nullptr;
        const float* udn = (l < 4) ? uAll + 640 + uoff[l + 1] : nullptr;
        if (O >= 64) {
            dim3 grid(gx, O / 64);
            gemm_mfma<64><<<grid, 256, 0, stream>>>(actA, wb[l], actB, gus, gud, lg, lg + N, N,
                                                    K, O);
        } else {
            dim3 grid(gx, 1);
            gemm_mfma<32><<<grid, 256, 0, stream>>>(actA, wb[l], actB, gus, gud, lg, lg + N, N,
                                                    K, O);
        }
        switch (O) {
            case 256:
                gat_aggregate<256><<<aggBlocks, 256, 0, stream>>>(
                    actB, lg, lg + N, rowptr, esrc, gb[l], actA, N, usn, udn, lgn, lgn + N);
                break;
            case 128:
                gat_aggregate<128><<<aggBlocks, 256, 0, stream>>>(
                    actB, lg, lg + N, rowptr, esrc, gb[l], actA, N, usn, udn, lgn, lgn + N);
                break;
            case 64:
                gat_aggregate<64><<<aggBlocks, 256, 0, stream>>>(
                    actB, lg, lg + N, rowptr, esrc, gb[l], actA, N, usn, udn, lgn, lgn + N);
                break;
            default:
                gat_aggregate<32><<<aggBlocks, 256, 0, stream>>>(
                    actB, lg, lg + N, rowptr, esrc, gb[l], actA, N, usn, udn, lgn, lgn + N);
                break;
        }
    }

    // 4. fused mean pool + linear + sigmoid
    pool_final_kernel<<<G, 256, 0, stream>>>(actA, gstart, lw, lb, out, G);
}